// Round 10
// baseline (871.823 us; speedup 1.0000x reference)
//
#include <hip/hip_runtime.h>

#define IN_DIM 128
#define OUT_DIM 64
#define PADF 36     // gemm LDS row stride in floats
#define BK_BITS 6   // 64-node buckets
#define BK_NODES 64
#define CPAD 16     // cursor/count padding: one int per 64B line

static inline size_t align_up(size_t v, size_t a) { return (v + a - 1) & ~(a - 1); }

// ---------- GEMM: h = x @ W ----------
// 256 threads = 4 waves; wave wv computes cols [16wv,16wv+16), lane = row.
// W loads wave-uniform -> s_load; acc[16] static -> VGPRs. (r6: left top-5)
__global__ __launch_bounds__(256, 8) void gemm_block(
    const float* __restrict__ x, const float* __restrict__ w,
    float* __restrict__ h, int nrows) {
  __shared__ float xt[64 * PADF];
  const int tid = threadIdx.x;
  const int lane = tid & 63;
  const int wv = __builtin_amdgcn_readfirstlane(tid >> 6);  // 0..3, SGPR
  const int rb = blockIdx.x * 64;

  float acc[16];
#pragma unroll
  for (int c = 0; c < 16; ++c) acc[c] = 0.f;

  const int r = tid >> 3;
  const int kq = (tid & 7) << 2;
  const float* wbase = w + wv * 16;

#pragma unroll 1
  for (int kc = 0; kc < IN_DIM; kc += 32) {
#pragma unroll
    for (int p = 0; p < 2; ++p) {
      int row = rb + r + p * 32;
      float4 v = (row < nrows)
                     ? *reinterpret_cast<const float4*>(x + (size_t)row * IN_DIM + kc + kq)
                     : make_float4(0.f, 0.f, 0.f, 0.f);
      *reinterpret_cast<float4*>(&xt[(r + p * 32) * PADF + kq]) = v;
    }
    __syncthreads();
#pragma unroll
    for (int k4 = 0; k4 < 32; k4 += 4) {
      float4 xv = *reinterpret_cast<const float4*>(&xt[lane * PADF + k4]);
#pragma unroll
      for (int kk = 0; kk < 4; ++kk) {
        float xs = (&xv.x)[kk];
        const float* wk = wbase + (size_t)(kc + k4 + kk) * OUT_DIM;  // uniform -> s_load
#pragma unroll
        for (int c = 0; c < 16; ++c)
          acc[c] = fmaf(xs, wk[c], acc[c]);
      }
    }
    __syncthreads();
  }

  int row = rb + lane;
  if (row < nrows) {
    float4* hp = reinterpret_cast<float4*>(h + (size_t)row * OUT_DIM + wv * 16);
#pragma unroll
    for (int c4 = 0; c4 < 4; ++c4)
      hp[c4] = make_float4(acc[c4 * 4], acc[c4 * 4 + 1], acc[c4 * 4 + 2], acc[c4 * 4 + 3]);
  }
}

// ---------- bucket CSR build ----------

__global__ __launch_bounds__(256) void zero_i32(int* __restrict__ p, int n) {
  int tid = blockIdx.x * blockDim.x + threadIdx.x;
  int stride = gridDim.x * blockDim.x;
  for (int i = tid; i < n; i += stride) p[i] = 0;
}

// Bucket histogram via per-block LDS (int LDS atomics are native ds_add_u32).
__global__ __launch_bounds__(256) void hist_lds_kernel(
    const int* __restrict__ dst, int nedges, int* __restrict__ counts_pad,
    int nb) {
  __shared__ int hcnt[2048];
  const int tid = threadIdx.x;
  for (int i = tid; i < nb; i += 256) hcnt[i] = 0;
  __syncthreads();
  int gid = blockIdx.x * blockDim.x + tid;
  int stride = gridDim.x * blockDim.x;
  for (int e = gid; e < nedges; e += stride) {
    int d = __builtin_nontemporal_load(dst + e);
    atomicAdd(&hcnt[d >> BK_BITS], 1);
  }
  __syncthreads();
  for (int i = tid; i < nb; i += 256) {
    int v = hcnt[i];
    if (v) atomicAdd(&counts_pad[i * CPAD], v);
  }
}

// Single-block exclusive scan of nb (<=2047) bucket counts.
__global__ __launch_bounds__(1024) void scan_buckets_kernel(
    const int* __restrict__ counts_pad, int nb, int* __restrict__ offsets,
    int* __restrict__ cursor_pad) {
  __shared__ int sb[2][2048];
  const int tid = threadIdx.x;
  const int i0 = tid * 2, i1 = tid * 2 + 1;
  sb[0][i0] = (i0 < nb) ? counts_pad[i0 * CPAD] : 0;
  sb[0][i1] = (i1 < nb) ? counts_pad[i1 * CPAD] : 0;
  __syncthreads();
  int cur = 0;
  for (int d = 1; d < 2048; d <<= 1) {
    int a0 = sb[cur][i0] + ((i0 >= d) ? sb[cur][i0 - d] : 0);
    int a1 = sb[cur][i1] + ((i1 >= d) ? sb[cur][i1 - d] : 0);
    sb[cur ^ 1][i0] = a0;
    sb[cur ^ 1][i1] = a1;
    cur ^= 1;
    __syncthreads();
  }
  if (i0 <= nb) {
    int e0 = (i0 == 0) ? 0 : sb[cur][i0 - 1];
    offsets[i0] = e0;
    if (i0 < nb) cursor_pad[i0 * CPAD] = e0;
  }
  if (i1 <= nb) {
    int e1 = sb[cur][i1 - 1];
    offsets[i1] = e1;
    if (i1 < nb) cursor_pad[i1 * CPAD] = e1;
  }
}

// XCD-range-partitioned bucket fill.
__global__ __launch_bounds__(256) void bucket_fill_kernel(
    const int* __restrict__ ei, const float* __restrict__ ew, int nedges,
    int* __restrict__ cursor_pad, int2* __restrict__ bucketed, int nb) {
  const int range = blockIdx.x & 7;
  const int ngroups = gridDim.x >> 3;
  const int group = blockIdx.x >> 3;
  const int lo = (int)((size_t)range * nb / 8);
  const int hi = (int)((size_t)(range + 1) * nb / 8);
  int tid = group * blockDim.x + threadIdx.x;
  int stride = ngroups * blockDim.x;
  for (int e = tid; e < nedges; e += stride) {
    int d = __builtin_nontemporal_load(ei + e);
    int b = d >> BK_BITS;
    if (b >= lo && b < hi) {
      int s = ei[nedges + e];
      float wv = ew[e];
      int p = atomicAdd(&cursor_pad[b * CPAD], 1);
      bucketed[p] = make_int2(s | ((d & (BK_NODES - 1)) << 20),
                              __float_as_int(wv));
    }
  }
}

// ---------- LDS-gather v2: one block per bucket ----------
// r9 falsified the CAS theory: bottleneck was the per-chunk DEPENDENT chain
// (wave-uniform meta load ~900cyc -> h load ~500cyc -> ds_add), ~230
// cyc/edge = 594us. Fix (r6's proven pattern): COALESCED meta (one int2
// vector load per 64 edges/lane-distinct), shfl broadcast (VALU, no mem
// latency), independent ILP-8 h loads, fire-and-forget ds_add_f32.
__global__ __launch_bounds__(256) void lds_gather_kernel(
    const int* __restrict__ offsets, const int2* __restrict__ bucketed,
    const float* __restrict__ h, const float* __restrict__ bias,
    float* __restrict__ out, int nnodes) {
  __shared__ float tile[BK_NODES * OUT_DIM];  // 16 KB
  const int tid = threadIdx.x;
  const int lane = tid & 63;
  const int wv = __builtin_amdgcn_readfirstlane(tid >> 6);
  const int b = blockIdx.x;

#pragma unroll
  for (int i = 0; i < BK_NODES * OUT_DIM / 256; ++i)
    tile[tid + i * 256] = 0.f;
  __syncthreads();

  const int beg = offsets[b];
  const int end = offsets[b + 1];

  // 4 waves take interleaved 64-edge chunks
  for (int base = beg + wv * 64; base < end; base += 256) {
    int cnt = min(64, end - base);
    int2 me = (lane < cnt) ? bucketed[base + lane] : make_int2(0, 0);
    int ms = me.x;                       // src | dl<<20
    float mw = __int_as_float(me.y);
    int j = 0;
    for (; j + 8 <= cnt; j += 8) {
      int p0 = __shfl(ms, j + 0), p1 = __shfl(ms, j + 1);
      int p2 = __shfl(ms, j + 2), p3 = __shfl(ms, j + 3);
      int p4 = __shfl(ms, j + 4), p5 = __shfl(ms, j + 5);
      int p6 = __shfl(ms, j + 6), p7 = __shfl(ms, j + 7);
      float w0 = __shfl(mw, j + 0), w1 = __shfl(mw, j + 1);
      float w2 = __shfl(mw, j + 2), w3 = __shfl(mw, j + 3);
      float w4 = __shfl(mw, j + 4), w5 = __shfl(mw, j + 5);
      float w6 = __shfl(mw, j + 6), w7 = __shfl(mw, j + 7);
      float g0 = h[(size_t)(p0 & 0xFFFFF) * OUT_DIM + lane];
      float g1 = h[(size_t)(p1 & 0xFFFFF) * OUT_DIM + lane];
      float g2 = h[(size_t)(p2 & 0xFFFFF) * OUT_DIM + lane];
      float g3 = h[(size_t)(p3 & 0xFFFFF) * OUT_DIM + lane];
      float g4 = h[(size_t)(p4 & 0xFFFFF) * OUT_DIM + lane];
      float g5 = h[(size_t)(p5 & 0xFFFFF) * OUT_DIM + lane];
      float g6 = h[(size_t)(p6 & 0xFFFFF) * OUT_DIM + lane];
      float g7 = h[(size_t)(p7 & 0xFFFFF) * OUT_DIM + lane];
      unsafeAtomicAdd(&tile[((p0 >> 20) & 63) * OUT_DIM + lane], w0 * g0);
      unsafeAtomicAdd(&tile[((p1 >> 20) & 63) * OUT_DIM + lane], w1 * g1);
      unsafeAtomicAdd(&tile[((p2 >> 20) & 63) * OUT_DIM + lane], w2 * g2);
      unsafeAtomicAdd(&tile[((p3 >> 20) & 63) * OUT_DIM + lane], w3 * g3);
      unsafeAtomicAdd(&tile[((p4 >> 20) & 63) * OUT_DIM + lane], w4 * g4);
      unsafeAtomicAdd(&tile[((p5 >> 20) & 63) * OUT_DIM + lane], w5 * g5);
      unsafeAtomicAdd(&tile[((p6 >> 20) & 63) * OUT_DIM + lane], w6 * g6);
      unsafeAtomicAdd(&tile[((p7 >> 20) & 63) * OUT_DIM + lane], w7 * g7);
    }
    for (; j < cnt; ++j) {
      int p = __shfl(ms, j);
      float wj = __shfl(mw, j);
      float g = h[(size_t)(p & 0xFFFFF) * OUT_DIM + lane];
      unsafeAtomicAdd(&tile[((p >> 20) & 63) * OUT_DIM + lane], wj * g);
    }
  }
  __syncthreads();

  // writeout: 64 rows x 16 float4; bias fused
  const float4* bias4 = reinterpret_cast<const float4*>(bias);
  for (int i = tid; i < BK_NODES * 16; i += 256) {
    int r = i >> 4, c4 = i & 15;
    int node = (b << BK_BITS) + r;
    if (node < nnodes) {
      float4 t = *reinterpret_cast<const float4*>(&tile[r * OUT_DIM + c4 * 4]);
      float4 bb = bias4[c4];
      float4 o = make_float4(t.x + bb.x, t.y + bb.y, t.z + bb.z, t.w + bb.w);
      *reinterpret_cast<float4*>(&out[(size_t)node * OUT_DIM + c4 * 4]) = o;
    }
  }
}

extern "C" void kernel_launch(void* const* d_in, const int* in_sizes, int n_in,
                              void* d_out, int out_size, void* d_ws, size_t ws_size,
                              hipStream_t stream) {
  const float* x    = (const float*)d_in[0];
  const int*   ei   = (const int*)d_in[1];    // [2, E]: row0 = dst, row1 = src
  const float* ew   = (const float*)d_in[2];
  const float* w    = (const float*)d_in[3];
  const float* bias = (const float*)d_in[4];
  float* out = (float*)d_out;

  const int nrows  = in_sizes[0] / IN_DIM;  // 100000
  const int nedges = in_sizes[2];           // 1600000
  const int nb     = (nrows + BK_NODES - 1) >> BK_BITS;  // 1563

  // ws layout
  char* ws = (char*)d_ws;
  size_t o = 0;
  float* h = (float*)(ws + o);            o += align_up((size_t)nrows * OUT_DIM * 4, 512);
  int* counts_pad = (int*)(ws + o);       o += align_up((size_t)nb * CPAD * 4, 512);
  int* cursor_pad = (int*)(ws + o);       o += align_up((size_t)nb * CPAD * 4, 512);
  int* offsets    = (int*)(ws + o);       o += align_up((size_t)(nb + 1) * 4, 512);
  int2* bucketed  = (int2*)(ws + o);      o += align_up((size_t)nedges * 8, 512);

  hipLaunchKernelGGL(gemm_block, dim3((nrows + 63) / 64), dim3(256), 0, stream,
                     x, w, h, nrows);
  hipLaunchKernelGGL(zero_i32, dim3(64), dim3(256), 0, stream,
                     counts_pad, nb * CPAD);
  hipLaunchKernelGGL(hist_lds_kernel, dim3(256), dim3(256), 0, stream,
                     ei, nedges, counts_pad, nb);
  hipLaunchKernelGGL(scan_buckets_kernel, dim3(1), dim3(1024), 0, stream,
                     counts_pad, nb, offsets, cursor_pad);
  hipLaunchKernelGGL(bucket_fill_kernel, dim3(2048), dim3(256), 0, stream,
                     ei, ew, nedges, cursor_pad, bucketed, nb);
  hipLaunchKernelGGL(lds_gather_kernel, dim3(nb), dim3(256), 0, stream,
                     offsets, bucketed, h, bias, out, nrows);
}

// Round 11
// 352.743 us; speedup vs baseline: 2.4716x; 2.4716x over previous
//
#include <hip/hip_runtime.h>

#define IN_DIM 128
#define OUT_DIM 64
#define PADF 36  // gemm LDS row stride in floats

static inline size_t align_up(size_t v, size_t a) { return (v + a - 1) & ~(a - 1); }

// ---------- GEMM: h = x @ W ----------
// 256 threads = 4 waves; wave wv computes cols [16wv,16wv+16), lane = row.
// W loads wave-uniform -> s_load; acc[16] static -> VGPRs. (proven in r6's 335)
__global__ __launch_bounds__(256, 8) void gemm_block(
    const float* __restrict__ x, const float* __restrict__ w,
    float* __restrict__ h, int nrows) {
  __shared__ float xt[64 * PADF];
  const int tid = threadIdx.x;
  const int lane = tid & 63;
  const int wv = __builtin_amdgcn_readfirstlane(tid >> 6);  // 0..3, SGPR
  const int rb = blockIdx.x * 64;

  float acc[16];
#pragma unroll
  for (int c = 0; c < 16; ++c) acc[c] = 0.f;

  const int r = tid >> 3;
  const int kq = (tid & 7) << 2;
  const float* wbase = w + wv * 16;

#pragma unroll 1
  for (int kc = 0; kc < IN_DIM; kc += 32) {
#pragma unroll
    for (int p = 0; p < 2; ++p) {
      int row = rb + r + p * 32;
      float4 v = (row < nrows)
                     ? *reinterpret_cast<const float4*>(x + (size_t)row * IN_DIM + kc + kq)
                     : make_float4(0.f, 0.f, 0.f, 0.f);
      *reinterpret_cast<float4*>(&xt[(r + p * 32) * PADF + kq]) = v;
    }
    __syncthreads();
#pragma unroll
    for (int k4 = 0; k4 < 32; k4 += 4) {
      float4 xv = *reinterpret_cast<const float4*>(&xt[lane * PADF + k4]);
#pragma unroll
      for (int kk = 0; kk < 4; ++kk) {
        float xs = (&xv.x)[kk];
        const float* wk = wbase + (size_t)(kc + k4 + kk) * OUT_DIM;  // uniform -> s_load
#pragma unroll
        for (int c = 0; c < 16; ++c)
          acc[c] = fmaf(xs, wk[c], acc[c]);
      }
    }
    __syncthreads();
  }

  int row = rb + lane;
  if (row < nrows) {
    float4* hp = reinterpret_cast<float4*>(h + (size_t)row * OUT_DIM + wv * 16);
#pragma unroll
    for (int c4 = 0; c4 < 4; ++c4)
      hp[c4] = make_float4(acc[c4 * 4], acc[c4 * 4 + 1], acc[c4 * 4 + 2], acc[c4 * 4 + 3]);
  }
}

// ---------- per-dst CSR build (r6 structure, no nt) ----------

__global__ __launch_bounds__(256) void zero_i32(int* __restrict__ p, int n) {
  int tid = blockIdx.x * blockDim.x + threadIdx.x;
  int stride = gridDim.x * blockDim.x;
  for (int i = tid; i < n; i += stride) p[i] = 0;
}

__global__ __launch_bounds__(256) void hist_kernel(
    const int* __restrict__ dst, int nedges, int* __restrict__ counts) {
  int tid = blockIdx.x * blockDim.x + threadIdx.x;
  int stride = gridDim.x * blockDim.x;
  for (int e = tid; e < nedges; e += stride) atomicAdd(&counts[dst[e]], 1);
}

__global__ __launch_bounds__(1024) void scan_block(
    const int* __restrict__ counts, int n, int* __restrict__ offsets,
    int* __restrict__ bsums) {
  __shared__ int buf[1024];
  int gid = blockIdx.x * 1024 + threadIdx.x;
  int v = (gid < n) ? counts[gid] : 0;
  buf[threadIdx.x] = v;
  __syncthreads();
  for (int d = 1; d < 1024; d <<= 1) {
    int t = (threadIdx.x >= d) ? buf[threadIdx.x - d] : 0;
    __syncthreads();
    buf[threadIdx.x] += t;
    __syncthreads();
  }
  if (gid < n) offsets[gid] = buf[threadIdx.x] - v;  // exclusive
  if (threadIdx.x == 1023) bsums[blockIdx.x] = buf[1023];
}

__global__ void scan_bsums(int* __restrict__ bsums, int nb) {
  if (threadIdx.x == 0 && blockIdx.x == 0) {
    int run = 0;
    for (int i = 0; i < nb; ++i) { int v = bsums[i]; bsums[i] = run; run += v; }
  }
}

__global__ __launch_bounds__(256) void add_bsums(
    int* __restrict__ offsets, const int* __restrict__ bsums, int n,
    int* __restrict__ cursor, int nnodes) {
  int tid = blockIdx.x * blockDim.x + threadIdx.x;
  int stride = gridDim.x * blockDim.x;
  for (int i = tid; i < n; i += stride) {
    int o = offsets[i] + bsums[i >> 10];
    offsets[i] = o;
    if (i < nnodes) cursor[i] = o;
  }
}

// 16-range fill: each XCD (blockIdx&7) handles TWO node-ranges sequentially.
// r6 counters: WRITE 95 MB for 12.8 MB payload -> open-tail-line window
// (1.6 MB/XCD) thrashed by the edge-read stream. Halving the window to
// 800 KB should ~halve premature evictions; the extra dst scan re-reads
// hit L3 (edge arrays 19.2 MB resident).
__global__ __launch_bounds__(256) void fill_part16_kernel(
    const int* __restrict__ ei, const float* __restrict__ ew, int nedges,
    int* __restrict__ cursor, int2* __restrict__ csr, int nnodes) {
  const int xcd = blockIdx.x & 7;
  const int ngroups = gridDim.x >> 3;
  const int group = blockIdx.x >> 3;
  const int tid0 = group * blockDim.x + threadIdx.x;
  const int stride = ngroups * blockDim.x;
#pragma unroll 1
  for (int sub = 0; sub < 2; ++sub) {
    const int range = xcd * 2 + sub;
    const int lo = (int)((size_t)range * nnodes / 16);
    const int hi = (int)((size_t)(range + 1) * nnodes / 16);
    for (int e = tid0; e < nedges; e += stride) {
      int d = ei[e];
      if (d >= lo && d < hi) {
        int s = ei[nedges + e];
        float wv = ew[e];
        int p = atomicAdd(&cursor[d], 1);
        csr[p] = make_int2(s, __float_as_int(wv));
      }
    }
  }
}

// ---------- gather: out[dst] = bias + sum_e w_e * h[src_e] ----------
// One wave per node; lane = channel; register accumulator (the structure
// that ran <=76 us in r6/r7 -- compiler keeps 8 h-loads in flight).
__global__ __launch_bounds__(256) void gather_kernel(
    const int* __restrict__ offsets, const int2* __restrict__ csr,
    const float* __restrict__ h, const float* __restrict__ bias,
    float* __restrict__ out, int nnodes) {
  const int lane = threadIdx.x & 63;
  const int wid = blockIdx.x * (blockDim.x >> 6) + (threadIdx.x >> 6);
  const int nw = gridDim.x * (blockDim.x >> 6);
  const float b = bias[lane];

  for (int node = wid; node < nnodes; node += nw) {
    int beg = offsets[node];
    int end = offsets[node + 1];
    float acc = 0.f;
    for (int eo = beg; eo < end; eo += 64) {
      int cnt = min(64, end - eo);
      int2 me = (lane < cnt) ? csr[eo + lane] : make_int2(0, 0);
      int ms = me.x;
      float mw = __int_as_float(me.y);
      for (int j = 0; j < cnt; j += 8) {
        int s0 = __shfl(ms, j + 0), s1 = __shfl(ms, j + 1);
        int s2 = __shfl(ms, j + 2), s3 = __shfl(ms, j + 3);
        int s4 = __shfl(ms, j + 4), s5 = __shfl(ms, j + 5);
        int s6 = __shfl(ms, j + 6), s7 = __shfl(ms, j + 7);
        float w0 = __shfl(mw, j + 0), w1 = __shfl(mw, j + 1);
        float w2 = __shfl(mw, j + 2), w3 = __shfl(mw, j + 3);
        float w4 = __shfl(mw, j + 4), w5 = __shfl(mw, j + 5);
        float w6 = __shfl(mw, j + 6), w7 = __shfl(mw, j + 7);
        float h0 = h[(size_t)s0 * OUT_DIM + lane];
        float h1 = h[(size_t)s1 * OUT_DIM + lane];
        float h2 = h[(size_t)s2 * OUT_DIM + lane];
        float h3 = h[(size_t)s3 * OUT_DIM + lane];
        float h4 = h[(size_t)s4 * OUT_DIM + lane];
        float h5 = h[(size_t)s5 * OUT_DIM + lane];
        float h6 = h[(size_t)s6 * OUT_DIM + lane];
        float h7 = h[(size_t)s7 * OUT_DIM + lane];
        acc = fmaf(w0, h0, acc);
        acc = fmaf(w1, h1, acc);
        acc = fmaf(w2, h2, acc);
        acc = fmaf(w3, h3, acc);
        acc = fmaf(w4, h4, acc);
        acc = fmaf(w5, h5, acc);
        acc = fmaf(w6, h6, acc);
        acc = fmaf(w7, h7, acc);
      }
    }
    out[(size_t)node * OUT_DIM + lane] = acc + b;
  }
}

extern "C" void kernel_launch(void* const* d_in, const int* in_sizes, int n_in,
                              void* d_out, int out_size, void* d_ws, size_t ws_size,
                              hipStream_t stream) {
  const float* x    = (const float*)d_in[0];
  const int*   ei   = (const int*)d_in[1];    // [2, E]: row0 = dst, row1 = src
  const float* ew   = (const float*)d_in[2];
  const float* w    = (const float*)d_in[3];
  const float* bias = (const float*)d_in[4];
  float* out = (float*)d_out;

  const int nrows  = in_sizes[0] / IN_DIM;  // 100000
  const int nedges = in_sizes[2];           // 1600000
  const int nscan  = nrows + 1;
  const int nblk   = (nscan + 1023) / 1024;

  // ws layout
  char* ws = (char*)d_ws;
  size_t o = 0;
  float* h = (float*)(ws + o);           o += align_up((size_t)nrows * OUT_DIM * 4, 512);
  int* counts  = (int*)(ws + o);         o += align_up((size_t)nscan * 4, 512);
  int* offsets = (int*)(ws + o);         o += align_up((size_t)nscan * 4, 512);
  int* cursor  = (int*)(ws + o);         o += align_up((size_t)nrows * 4, 512);
  int* bsums   = (int*)(ws + o);         o += align_up((size_t)nblk * 4, 512);
  int2* csr    = (int2*)(ws + o);        o += align_up((size_t)nedges * 8, 512);

  hipLaunchKernelGGL(gemm_block, dim3((nrows + 63) / 64), dim3(256), 0, stream,
                     x, w, h, nrows);
  hipLaunchKernelGGL(zero_i32, dim3(128), dim3(256), 0, stream, counts, nscan);
  hipLaunchKernelGGL(hist_kernel, dim3(2048), dim3(256), 0, stream,
                     ei, nedges, counts);
  hipLaunchKernelGGL(scan_block, dim3(nblk), dim3(1024), 0, stream,
                     counts, nscan, offsets, bsums);
  hipLaunchKernelGGL(scan_bsums, dim3(1), dim3(64), 0, stream, bsums, nblk);
  hipLaunchKernelGGL(add_bsums, dim3(128), dim3(256), 0, stream,
                     offsets, bsums, nscan, cursor, nrows);
  hipLaunchKernelGGL(fill_part16_kernel, dim3(2048), dim3(256), 0, stream,
                     ei, ew, nedges, cursor, csr, nrows);
  hipLaunchKernelGGL(gather_kernel, dim3(8192), dim3(256), 0, stream,
                     offsets, csr, h, bias, out, nrows);
}